// Round 8
// baseline (37.786 us; speedup 1.0000x reference)
//
#include <hip/hip_runtime.h>
#include <math.h>

#define KG_B    16384
#define KG_D    128
#define KG_NR   24
#define KG_TM   32                        // elements per block
#define KG_BPAD (KG_B + KG_NR * KG_TM)    // 17152
#define KG_NGRP (KG_BPAD / KG_TM)         // 536

// ws layout: int perm[KG_BPAD] (bytes 0..68608)
//            | u64 acc @ byte 68608 | u32 done @ byte 68616
//            | ushort preW[24*16384] @ byte 131072
#define WS_ACC_BYTES  68608
#define WS_DONE_BYTES 68616
#define WS_PREW_BYTES 131072
#define KG_SCALE      1099511627776.0     // 2^40

typedef __attribute__((ext_vector_type(8))) short bf16x8;
typedef __attribute__((ext_vector_type(4))) float f32x4;

__device__ __forceinline__ unsigned bf16r(float f) {
    return (__float_as_uint(f) + 0x8000u) >> 16;
}
__device__ __forceinline__ unsigned pack2(float lo, float hi) {
    return bf16r(lo) | (bf16r(hi) << 16);
}

// ---- K1: block 0 = fused relation sort (+ counter reset);
//      blocks 1..24 = W^T bf16 prep into swizzled preW image. ----
__global__ __launch_bounds__(1024) void kg_sort_prep(const int* __restrict__ r,
                                                     const float* __restrict__ M,
                                                     int* __restrict__ perm,
                                                     unsigned long long* __restrict__ acc,
                                                     unsigned int* __restrict__ done,
                                                     unsigned short* __restrict__ preW) {
    __shared__ int cntw[16][25];
    __shared__ int basew[16][25];
    __shared__ int pbase_s[24];
    __shared__ int cnt_tot[24];
    __shared__ int total_s;
    __shared__ __align__(16) unsigned short sWp[KG_D * KG_D];   // 32 KB (prep path)

    const int t = threadIdx.x;

    if (blockIdx.x != 0) {
        // ---------- prep path: transpose+pack one 128x128 matrix ----------
        const int k  = blockIdx.x - 1;
        const int e  = t >> 3;              // 0..127
        const int c0 = (t & 7) * 16;
        const float* src = M + ((size_t)k << 14) + (size_t)e * KG_D + c0;
        float4 rw[4];
#pragma unroll
        for (int f = 0; f < 4; ++f) rw[f] = ((const float4*)src)[f];
#pragma unroll
        for (int dc = 0; dc < 16; ++dc) {
            const int col = c0 + dc;
            const float v = ((const float*)&rw[0])[dc];
            sWp[col * KG_D + (e ^ ((col & 7) << 3))] = (unsigned short)bf16r(v);
        }
        __syncthreads();
        uint4* dst = (uint4*)(preW + ((size_t)k << 14));
        const uint4* s4 = (const uint4*)sWp;
        dst[2 * t]     = s4[2 * t];
        dst[2 * t + 1] = s4[2 * t + 1];
        return;
    }

    // ---------- sort path (single block) ----------
    if (t == 0) { *acc = 0ull; *done = 0u; }   // reset per call (ordered vs kg_main)

    const int w = t >> 6;
    int* cz = &cntw[0][0];
    for (int i = t; i < 16 * 25; i += 1024) cz[i] = 0;
    __syncthreads();

    int kt[16];
#pragma unroll
    for (int j = 0; j < 16; ++j) kt[j] = r[j * 1024 + t];
#pragma unroll
    for (int j = 0; j < 16; ++j) atomicAdd(&cntw[w][kt[j]], 1);
    __syncthreads();

    if (t < 24) {
        int s = 0;
        for (int w2 = 0; w2 < 16; ++w2) { basew[w2][t] = s; s += cntw[w2][t]; }
        cnt_tot[t] = s;
    }
    __syncthreads();
    if (t == 0) {
        int run = 0;
        for (int k = 0; k < 24; ++k) {
            pbase_s[k] = run;
            run += (cnt_tot[k] + (KG_TM - 1)) & ~(KG_TM - 1);
        }
        total_s = run;
    }
    __syncthreads();
    if (t < 24)
        for (int w2 = 0; w2 < 16; ++w2) basew[w2][t] += pbase_s[t];
    for (int i = t; i < 16 * 25; i += 1024) cz[i] = 0;   // reuse cntw as cur
    __syncthreads();

#pragma unroll
    for (int j = 0; j < 16; ++j) {
        const int k = kt[j];
        const int pos = basew[w][k] + atomicAdd(&cntw[w][k], 1);
        perm[pos] = j * 1024 + t;
    }
    __syncthreads();

    if (t < 24) {
        const int e0 = pbase_s[t] + cnt_tot[t];
        const int e1 = pbase_s[t] + ((cnt_tot[t] + (KG_TM - 1)) & ~(KG_TM - 1));
        for (int p = e0; p < e1; ++p) perm[p] = -1;
    }
    for (int i = total_s + t; i < KG_BPAD; i += 1024) perm[i] = -1;
}

// ---- K2: MFMA main + fused deterministic reduction.
//      Block = 32 same-relation elements, 4 waves: rt=w&1 rows, chs=w>>1 cols.
//      A-fragments loaded per-lane direct from ent (no sX round-trip). ----
__global__ __launch_bounds__(256, 3) void kg_main(
    const float* __restrict__ ent, const float* __restrict__ rel,
    const unsigned short* __restrict__ preW,
    const int* __restrict__ h,     const int* __restrict__ r,
    const int* __restrict__ pt,    const int* __restrict__ nt,
    const int* __restrict__ perm,
    unsigned long long* __restrict__ acc,
    unsigned int* __restrict__ done,
    float* __restrict__ out)
{
    __shared__ __align__(16) unsigned short sW[KG_D * KG_D];   // 32 KB
    __shared__ float sScr[2][KG_TM][4];

    const int tid   = threadIdx.x;
    const int slot0 = blockIdx.x * KG_TM;
    const int p0    = perm[slot0];

    float bs = 0.f;                       // block sum lives at tid==0

    if (p0 >= 0) {                        // uniform branch per block
        const int rb = __builtin_amdgcn_readfirstlane(r[p0]);

        // ---- stage W: async linear copy of the prepped swizzled image ----
        {
            const char* gsrc = (const char*)(preW + ((size_t)rb << 14));
            char* ldsb = (char*)&sW[0];
            const int w4   = tid >> 6;
            const int lane = tid & 63;
#pragma unroll
            for (int q = 0; q < 8; ++q) {
                const int off = q * 4096 + w4 * 1024;
                __builtin_amdgcn_global_load_lds(
                    (const unsigned int*)(gsrc + off + lane * 16),
                    (unsigned int*)(ldsb + off), 16, 0, 0);
            }
        }

        const int l   = tid & 63;
        const int w   = tid >> 6;
        const int rt  = w & 1;
        const int chs = w >> 1;
        const int li  = l & 15;
        const int kq  = l >> 4;

        // ---- per-lane A fragments: direct gather + bf16 pack (pre-barrier) ----
        const int ar = rt * 16 + li;                 // element row in block
        const int pr = perm[slot0 + ar];
        const int bb = pr < 0 ? p0 : pr;
        const int idx3[3] = { h[bb], pt[bb], nt[bb] };
        bf16x8 af[3][4];
#pragma unroll
        for (int t3 = 0; t3 < 3; ++t3) {
            const float* xb = ent + (size_t)idx3[t3] * KG_D;
#pragma unroll
            for (int kk = 0; kk < 4; ++kk) {
                const int e0 = kk * 32 + kq * 8;
                const float4 a0 = *(const float4*)(xb + e0);
                const float4 a1 = *(const float4*)(xb + e0 + 4);
                union { uint4 u; bf16x8 v; } cv;
                cv.u.x = pack2(a0.x, a0.y); cv.u.y = pack2(a0.z, a0.w);
                cv.u.z = pack2(a1.x, a1.y); cv.u.w = pack2(a1.z, a1.w);
                af[t3][kk] = cv.v;
            }
        }
        __syncthreads();                  // drains W global_load_lds (vmcnt)

        f32x4 accf[3][4];
#pragma unroll
        for (int t3 = 0; t3 < 3; ++t3)
#pragma unroll
            for (int n = 0; n < 4; ++n) accf[t3][n] = (f32x4)0.f;

#pragma unroll
        for (int kk = 0; kk < 4; ++kk) {
            const int e0 = kk * 32 + kq * 8;
#pragma unroll
            for (int n = 0; n < 4; ++n) {
                const int col = chs * 64 + n * 16 + li;
                const bf16x8 bfr = *(const bf16x8*)&sW[col * KG_D + (e0 ^ ((col & 7) << 3))];
                accf[0][n] = __builtin_amdgcn_mfma_f32_16x16x32_bf16(af[0][kk], bfr, accf[0][n], 0, 0, 0);
                accf[1][n] = __builtin_amdgcn_mfma_f32_16x16x32_bf16(af[1][kk], bfr, accf[1][n], 0, 0, 0);
                accf[2][n] = __builtin_amdgcn_mfma_f32_16x16x32_bf16(af[2][kk], bfr, accf[2][n], 0, 0, 0);
            }
        }

        // ---- epilogue: C/D layout col=lane&15, row=(lane>>4)*4+reg ----
        float ps[4] = {0,0,0,0}, ns[4] = {0,0,0,0}, sq[4] = {0,0,0,0};
        const float* relrow = rel + (size_t)rb * KG_D + chs * 64;
#pragma unroll
        for (int n = 0; n < 4; ++n) {
            const float rv = relrow[n * 16 + li];
#pragma unroll
            for (int j = 0; j < 4; ++j) {
                const float va = accf[0][n][j];
                const float vp = accf[1][n][j];
                const float vn = accf[2][n][j];
                const float s  = va + rv;
                const float dp = s - vp;
                const float dn = s - vn;
                ps[j] += dp * dp;
                ns[j] += dn * dn;
                sq[j] += va * va + vp * vp + vn * vn + rv * rv;
            }
        }
#pragma unroll
        for (int j = 0; j < 4; ++j)
#pragma unroll
            for (int m = 1; m < 16; m <<= 1) {
                ps[j] += __shfl_xor(ps[j], m);
                ns[j] += __shfl_xor(ns[j], m);
                sq[j] += __shfl_xor(sq[j], m);
            }

        if (li == 0) {
#pragma unroll
            for (int j = 0; j < 4; ++j) {
                const int row = rt * 16 + kq * 4 + j;
                sScr[chs][row][0] = ps[j];
                sScr[chs][row][1] = ns[j];
                sScr[chs][row][2] = sq[j];
            }
        }
        __syncthreads();

        if (tid < 64) {
            float term = 0.f;
            if (tid < KG_TM) {
                const int row = tid;
                const float P = sScr[0][row][0] + sScr[1][row][0];
                const float N = sScr[0][row][1] + sScr[1][row][1];
                const float S = sScr[0][row][2] + sScr[1][row][2];
                const int pg = perm[slot0 + row];
                if (pg >= 0) {
                    const float x = P - N;                          // pos - neg
                    term = fmaxf(x, 0.f) + log1pf(expf(-fabsf(x)))  // softplus
                         + 5e-6f * S;                               // lambda/2 * l2
                }
            }
#pragma unroll
            for (int off = 16; off > 0; off >>= 1) term += __shfl_down(term, off);
            bs = term;                     // valid at tid==0
        }
    }

    // ---- deterministic fixed-point accumulate + last-block finalize ----
    if (tid == 0) {
        if (bs > 0.f)
            atomicAdd(acc, (unsigned long long)__double2ll_rn((double)bs * KG_SCALE));
        __threadfence();
        if (atomicAdd(done, 1u) == (unsigned)(KG_NGRP - 1)) {
            const unsigned long long tot = atomicAdd(acc, 0ull);
            out[0] = (float)((double)tot * (1.0 / KG_SCALE) * (1.0 / (double)KG_B));
        }
    }
}

extern "C" void kernel_launch(void* const* d_in, const int* in_sizes, int n_in,
                              void* d_out, int out_size, void* d_ws, size_t ws_size,
                              hipStream_t stream) {
    const float* ent = (const float*)d_in[0];
    const float* rel = (const float*)d_in[1];
    const float* M   = (const float*)d_in[2];
    const int*   h   = (const int*)d_in[3];
    const int*   r   = (const int*)d_in[4];
    const int*   pt  = (const int*)d_in[5];
    const int*   nt  = (const int*)d_in[6];

    int*                perm = (int*)d_ws;
    unsigned long long* acc  = (unsigned long long*)((char*)d_ws + WS_ACC_BYTES);
    unsigned int*       done = (unsigned int*)((char*)d_ws + WS_DONE_BYTES);
    unsigned short*     preW = (unsigned short*)((char*)d_ws + WS_PREW_BYTES);
    float*              out  = (float*)d_out;

    kg_sort_prep<<<1 + KG_NR, 1024, 0, stream>>>(r, M, perm, acc, done, preW);
    kg_main     <<<KG_NGRP, 256, 0, stream>>>(ent, rel, preW, h, r, pt, nt, perm,
                                              acc, done, out);
}

// Round 9
// 28.624 us; speedup vs baseline: 1.3201x; 1.3201x over previous
//
#include <hip/hip_runtime.h>
#include <math.h>

#define KG_B    16384
#define KG_D    128
#define KG_NR   24
#define KG_TM   32                        // elements per block
#define KG_BPAD (KG_B + KG_NR * KG_TM)    // 17152
#define KG_NGRP (KG_BPAD / KG_TM)         // 536

// ws layout: int perm[KG_BPAD] | float bsum[KG_NGRP] | (at byte 131072) ushort preW[24*16384]
#define WS_BSUM KG_BPAD
#define WS_PREW_BYTES 131072

typedef __attribute__((ext_vector_type(8))) short bf16x8;
typedef __attribute__((ext_vector_type(4))) float f32x4;

__device__ __forceinline__ unsigned bf16r(float f) {
    return (__float_as_uint(f) + 0x8000u) >> 16;
}
__device__ __forceinline__ unsigned pack2(float lo, float hi) {
    return bf16r(lo) | (bf16r(hi) << 16);
}

// ---- K1: block 0 = fused relation sort; blocks 1..24 = W^T bf16 prep ----
// preW[k] = W_k^T, PLAIN col-major bf16: preW[k][col*128 + e] = bf16(W[k][e][col]).
// MFMA B-fragment (col, e0) is then 8 consecutive bf16 -> one 16B load;
// the 4 kq-lanes of a col share one 64B line (line-efficient from L2).
__global__ __launch_bounds__(1024) void kg_sort_prep(const int* __restrict__ r,
                                                     const float* __restrict__ M,
                                                     int* __restrict__ perm,
                                                     unsigned short* __restrict__ preW) {
    __shared__ int cntw[16][25];
    __shared__ int basew[16][25];
    __shared__ int pbase_s[24];
    __shared__ int cnt_tot[24];
    __shared__ int total_s;
    __shared__ __align__(16) unsigned short sWp[KG_D * KG_D];   // 32 KB (prep path)

    const int t = threadIdx.x;

    if (blockIdx.x != 0) {
        // ---------- prep path: transpose+pack one 128x128 matrix ----------
        const int k  = blockIdx.x - 1;
        const int e  = t >> 3;              // 0..127
        const int c0 = (t & 7) * 16;
        const float* src = M + ((size_t)k << 14) + (size_t)e * KG_D + c0;
        float4 rw[4];
#pragma unroll
        for (int f = 0; f < 4; ++f) rw[f] = ((const float4*)src)[f];
#pragma unroll
        for (int dc = 0; dc < 16; ++dc) {
            const int col = c0 + dc;
            const float v = ((const float*)&rw[0])[dc];
            sWp[col * KG_D + e] = (unsigned short)bf16r(v);
        }
        __syncthreads();
        uint4* dst = (uint4*)(preW + ((size_t)k << 14));
        const uint4* s4 = (const uint4*)sWp;
        dst[2 * t]     = s4[2 * t];
        dst[2 * t + 1] = s4[2 * t + 1];
        return;
    }

    // ---------- sort path (single block) ----------
    const int w = t >> 6;
    int* cz = &cntw[0][0];
    for (int i = t; i < 16 * 25; i += 1024) cz[i] = 0;
    __syncthreads();

    int kt[16];
#pragma unroll
    for (int j = 0; j < 16; ++j) kt[j] = r[j * 1024 + t];
#pragma unroll
    for (int j = 0; j < 16; ++j) atomicAdd(&cntw[w][kt[j]], 1);
    __syncthreads();

    if (t < 24) {
        int s = 0;
        for (int w2 = 0; w2 < 16; ++w2) { basew[w2][t] = s; s += cntw[w2][t]; }
        cnt_tot[t] = s;
    }
    __syncthreads();
    if (t == 0) {
        int run = 0;
        for (int k = 0; k < 24; ++k) {
            pbase_s[k] = run;
            run += (cnt_tot[k] + (KG_TM - 1)) & ~(KG_TM - 1);
        }
        total_s = run;
    }
    __syncthreads();
    if (t < 24)
        for (int w2 = 0; w2 < 16; ++w2) basew[w2][t] += pbase_s[t];
    for (int i = t; i < 16 * 25; i += 1024) cz[i] = 0;   // reuse cntw as cur
    __syncthreads();

#pragma unroll
    for (int j = 0; j < 16; ++j) {
        const int k = kt[j];
        const int pos = basew[w][k] + atomicAdd(&cntw[w][k], 1);
        perm[pos] = j * 1024 + t;
    }
    __syncthreads();

    if (t < 24) {
        const int e0 = pbase_s[t] + cnt_tot[t];
        const int e1 = pbase_s[t] + ((cnt_tot[t] + (KG_TM - 1)) & ~(KG_TM - 1));
        for (int p = e0; p < e1; ++p) perm[p] = -1;
    }
    for (int i = total_s + t; i < KG_BPAD; i += 1024) perm[i] = -1;
}

// ---- K2: MFMA main. Block = 32 same-relation elements, 4 waves:
//      rt=w&1 rows, chs=w>>1 cols. X staged in LDS (R7-verified);
//      B-fragments read DIRECT from L2-resident preW (no sW, 25KB LDS). ----
__global__ __launch_bounds__(256, 4) void kg_main(
    const float* __restrict__ ent, const float* __restrict__ rel,
    const unsigned short* __restrict__ preW,
    const int* __restrict__ h,     const int* __restrict__ r,
    const int* __restrict__ pt,    const int* __restrict__ nt,
    const int* __restrict__ perm,  float* __restrict__ bsum)
{
    __shared__ __align__(16) unsigned short sX[3 * KG_TM * KG_D];   // 24 KB
    __shared__ float sScr[2][KG_TM][4];

    const int tid   = threadIdx.x;
    const int slot0 = blockIdx.x * KG_TM;
    const int p0    = perm[slot0];
    if (p0 < 0) {
        if (tid == 0) bsum[blockIdx.x] = 0.f;
        return;
    }
    const int rb = __builtin_amdgcn_readfirstlane(r[p0]);

    // ---- stage X: thread t -> row g=t>>3, 16 dims at e0=(t&7)*16, 3 products ----
    {
        const int g  = tid >> 3;
        const int e0 = (tid & 7) * 16;
        const int pg = perm[slot0 + g];
        const int bb = pg < 0 ? p0 : pg;
        const int idx3[3] = { h[bb], pt[bb], nt[bb] };
        const int sw = (g & 7) << 3;
#pragma unroll
        for (int t3 = 0; t3 < 3; ++t3) {
            const float* src = ent + (size_t)idx3[t3] * KG_D + e0;
            const float4 f0 = ((const float4*)src)[0];
            const float4 f1 = ((const float4*)src)[1];
            const float4 f2 = ((const float4*)src)[2];
            const float4 f3 = ((const float4*)src)[3];
            uint4 u0, u1;
            u0.x = pack2(f0.x, f0.y); u0.y = pack2(f0.z, f0.w);
            u0.z = pack2(f1.x, f1.y); u0.w = pack2(f1.z, f1.w);
            u1.x = pack2(f2.x, f2.y); u1.y = pack2(f2.z, f2.w);
            u1.z = pack2(f3.x, f3.y); u1.w = pack2(f3.z, f3.w);
            unsigned short* base = sX + t3 * (KG_TM * KG_D) + g * KG_D;
            *(uint4*)(base + ((e0    ) ^ sw)) = u0;
            *(uint4*)(base + ((e0 + 8) ^ sw)) = u1;
        }
    }
    __syncthreads();

    const int l   = tid & 63;
    const int w   = tid >> 6;
    const int rt  = w & 1;                 // row-tile (16 rows)
    const int chs = w >> 1;                // column half (64 cols)
    const int li  = l & 15;
    const int kq  = l >> 4;

    const int ar  = rt * 16 + li;
    const int asw = (ar & 7) << 3;

    const unsigned short* __restrict__ preWk = preW + ((size_t)rb << 14);

    f32x4 acc[3][4];
#pragma unroll
    for (int t3 = 0; t3 < 3; ++t3)
#pragma unroll
        for (int n = 0; n < 4; ++n) acc[t3][n] = (f32x4)0.f;

#pragma unroll
    for (int kk = 0; kk < 4; ++kk) {       // K chunks of 32
        const int e0 = kk * 32 + kq * 8;
        bf16x8 af[3];
#pragma unroll
        for (int t3 = 0; t3 < 3; ++t3)
            af[t3] = *(const bf16x8*)&sX[t3 * (KG_TM * KG_D) + ar * KG_D + (e0 ^ asw)];
#pragma unroll
        for (int n = 0; n < 4; ++n) {
            const int col = chs * 64 + n * 16 + li;
            const bf16x8 bfr = *(const bf16x8*)&preWk[col * KG_D + e0];
            acc[0][n] = __builtin_amdgcn_mfma_f32_16x16x32_bf16(af[0], bfr, acc[0][n], 0, 0, 0);
            acc[1][n] = __builtin_amdgcn_mfma_f32_16x16x32_bf16(af[1], bfr, acc[1][n], 0, 0, 0);
            acc[2][n] = __builtin_amdgcn_mfma_f32_16x16x32_bf16(af[2], bfr, acc[2][n], 0, 0, 0);
        }
    }

    // ---- epilogue: C/D layout col=lane&15, row=(lane>>4)*4+reg ----
    float ps[4] = {0,0,0,0}, ns[4] = {0,0,0,0}, sq[4] = {0,0,0,0};
    const float* relrow = rel + (size_t)rb * KG_D + chs * 64;
#pragma unroll
    for (int n = 0; n < 4; ++n) {
        const float rv = relrow[n * 16 + li];
#pragma unroll
        for (int j = 0; j < 4; ++j) {
            const float va = acc[0][n][j];
            const float vp = acc[1][n][j];
            const float vn = acc[2][n][j];
            const float s  = va + rv;
            const float dp = s - vp;
            const float dn = s - vn;
            ps[j] += dp * dp;
            ns[j] += dn * dn;
            sq[j] += va * va + vp * vp + vn * vn + rv * rv;
        }
    }
#pragma unroll
    for (int j = 0; j < 4; ++j)
#pragma unroll
        for (int m = 1; m < 16; m <<= 1) {
            ps[j] += __shfl_xor(ps[j], m);
            ns[j] += __shfl_xor(ns[j], m);
            sq[j] += __shfl_xor(sq[j], m);
        }

    if (li == 0) {
#pragma unroll
        for (int j = 0; j < 4; ++j) {
            const int row = rt * 16 + kq * 4 + j;
            sScr[chs][row][0] = ps[j];
            sScr[chs][row][1] = ns[j];
            sScr[chs][row][2] = sq[j];
        }
    }
    __syncthreads();

    if (tid < 64) {
        float term = 0.f;
        if (tid < KG_TM) {
            const int row = tid;
            const float P = sScr[0][row][0] + sScr[1][row][0];
            const float N = sScr[0][row][1] + sScr[1][row][1];
            const float S = sScr[0][row][2] + sScr[1][row][2];
            const int pg = perm[slot0 + row];
            if (pg >= 0) {
                const float x = P - N;                            // pos - neg
                term = fmaxf(x, 0.f) + log1pf(expf(-fabsf(x)))    // softplus
                     + 5e-6f * S;                                 // lambda/2 * l2
            }
        }
#pragma unroll
        for (int off = 16; off > 0; off >>= 1) term += __shfl_down(term, off);
        if (tid == 0) bsum[blockIdx.x] = term;
    }
}

// ---- K3: deterministic final reduction over 536 block sums ----
__global__ __launch_bounds__(256) void kg_final(const float* __restrict__ bsum,
                                                float* __restrict__ out) {
    __shared__ float s[256];
    const int t = threadIdx.x;
    float acc = 0.f;
    for (int i = t; i < KG_NGRP; i += 256) acc += bsum[i];
    s[t] = acc;
    __syncthreads();
    for (int off = 128; off > 0; off >>= 1) {
        if (t < off) s[t] += s[t + off];
        __syncthreads();
    }
    if (t == 0) out[0] = s[0] * (1.0f / (float)KG_B);
}

extern "C" void kernel_launch(void* const* d_in, const int* in_sizes, int n_in,
                              void* d_out, int out_size, void* d_ws, size_t ws_size,
                              hipStream_t stream) {
    const float* ent = (const float*)d_in[0];
    const float* rel = (const float*)d_in[1];
    const float* M   = (const float*)d_in[2];
    const int*   h   = (const int*)d_in[3];
    const int*   r   = (const int*)d_in[4];
    const int*   pt  = (const int*)d_in[5];
    const int*   nt  = (const int*)d_in[6];

    int*            perm = (int*)d_ws;
    float*          bsum = (float*)d_ws + WS_BSUM;
    unsigned short* preW = (unsigned short*)((char*)d_ws + WS_PREW_BYTES);
    float*          out  = (float*)d_out;

    kg_sort_prep<<<1 + KG_NR, 1024, 0, stream>>>(r, M, perm, preW);
    kg_main     <<<KG_NGRP, 256, 0, stream>>>(ent, rel, preW, h, r, pt, nt, perm, bsum);
    kg_final    <<<1, 256, 0, stream>>>(bsum, out);
}